// Round 1
// baseline (1015.851 us; speedup 1.0000x reference)
//
#include <hip/hip_runtime.h>

#define TT 216
#define BB 16384
#define LOG2E 1.44269504088896340736f

typedef _Float16 h16;
typedef _Float16 half8 __attribute__((ext_vector_type(8)));
typedef float f32x4 __attribute__((ext_vector_type(4)));

__device__ __forceinline__ float rcp_f(float v) { return __builtin_amdgcn_rcpf(v); }

// Gate preactivations arrive PRE-SCALED: pi,pf,po = -log2e*(preact), pg = 2*log2e*(preact).
// sigmoid(i) = 1/(1+2^pi), tanh(g) = (Eg-2)/Eg with Eg = 1+2^pg.
// c' = c/Ef + (Eg-2)/(Ei*Eg)  -> single rcp via common denominator.
// h  = (Ec-2)/(Eo*Ec),  Ec = 1+2^(2*log2e*c') (clamped to avoid inf*0=NaN).
__device__ __forceinline__ float lstm_up(float pi, float pf, float pg, float po, float& c)
{
    float ei = exp2f(pi), ef = exp2f(pf), eg = exp2f(pg);
    float Ei = 1.f + ei, Ef = 1.f + ef, Eg = 1.f + eg;
    float EiEg = Ei * Eg;
    float N = fmaf(c, EiEg, Ef * (Eg - 2.f));
    c = N * rcp_f(Ef * EiEg);
    float Eo = 1.f + exp2f(po);
    float pc = fminf(c * (2.f * LOG2E), 60.f);   // tanh saturates; clamp keeps Eo*Ec finite
    float Ec = 1.f + exp2f(pc);
    return (Ec - 2.f) * rcp_f(Eo * Ec);
}

// ---------------- weight prep: fp32 -> fp16, [N][K] fragment-ready, exp2-prescaled ----------
__global__ void prep_kernel(
    const float* __restrict__ Wih_f, const float* __restrict__ Whh_f,
    const float* __restrict__ bih_f, const float* __restrict__ bhh_f,
    const float* __restrict__ Wih_b, const float* __restrict__ Whh_b,
    const float* __restrict__ bih_b, const float* __restrict__ bhh_b,
    const float* __restrict__ Wih_m, const float* __restrict__ Whh_m,
    const float* __restrict__ bih_m, const float* __restrict__ bhh_m,
    h16* __restrict__ W1f, h16* __restrict__ W1b, h16* __restrict__ W2,
    float* __restrict__ b1f, float* __restrict__ b1b, float* __restrict__ b2)
{
    int gtid = blockIdx.x * blockDim.x + threadIdx.x;
    int gs = gridDim.x * blockDim.x;
    // small LSTMs: W1[n=64][k=32]: k 0..7 = x, 8..23 = h, 24..31 = zero pad
    for (int idx = gtid; idx < 64 * 32; idx += gs) {
        int n = idx >> 5, k = idx & 31;
        float a = ((n >> 4) == 2) ? 2.f * LOG2E : -LOG2E;
        float vf = 0.f, vb = 0.f;
        if (k < 8)       { vf = Wih_f[n * 8 + k];      vb = Wih_b[n * 8 + k]; }
        else if (k < 24) { vf = Whh_f[n * 16 + k - 8]; vb = Whh_b[n * 16 + k - 8]; }
        W1f[idx] = (h16)(vf * a);
        W1b[idx] = (h16)(vb * a);
    }
    for (int n = gtid; n < 64; n += gs) {
        float a = ((n >> 4) == 2) ? 2.f * LOG2E : -LOG2E;
        b1f[n] = (bih_f[n] + bhh_f[n]) * a;
        b1b[n] = (bih_b[n] + bhh_b[n]) * a;
    }
    // middle LSTM: W2[n=256][k=96]: k 0..31 = [hs_f|hs_b], 32..95 = h2
    for (int idx = gtid; idx < 256 * 96; idx += gs) {
        int n = idx / 96, k = idx - n * 96;
        float a = ((n >> 6) == 2) ? 2.f * LOG2E : -LOG2E;
        float v = (k < 32) ? Wih_m[n * 32 + k] : Whh_m[n * 64 + k - 32];
        W2[idx] = (h16)(v * a);
    }
    for (int n = gtid; n < 256; n += gs) {
        float a = ((n >> 6) == 2) ? 2.f * LOG2E : -LOG2E;
        b2[n] = (bih_m[n] + bhh_m[n]) * a;
    }
}

// ---------------- small LSTMs (fwd + bwd), MFMA 16x16x32 f16 ----------------
// block = 256 (4 waves), each wave = one M-tile of 16 batch rows, all 4 gate planes.
// grid = 2 dirs * 256 batch tiles of 64. hs out layout: [T][16][B] fp16 (unit-major).
__global__ __launch_bounds__(256, 2) void small_lstm_kernel(
    const float* __restrict__ x,
    const float* __restrict__ h0f, const float* __restrict__ c0f,
    const float* __restrict__ h0b, const float* __restrict__ c0b,
    const h16* __restrict__ W1f, const float* __restrict__ b1f,
    const h16* __restrict__ W1b, const float* __restrict__ b1b,
    h16* __restrict__ hsf, h16* __restrict__ hsb)
{
    __shared__ h16 Xs[2][64][40];   // [buf][batch row][k: 0..7 x, 8..23 h, 24..31 zero] (+pad)
    __shared__ h16 hst[16][68];     // unit-major coalescing buffer for hs flush

    const int tid = threadIdx.x;
    const int dir = blockIdx.x & 1;
    const int base = (blockIdx.x >> 1) * 64;
    const int w = tid >> 6, lane = tid & 63, col = lane & 15, q = lane >> 4;

    const float* h0 = dir ? h0b : h0f;
    const float* c0 = dir ? c0b : c0f;
    const h16* W1 = dir ? W1b : W1f;
    const float* b1 = dir ? b1b : b1f;
    h16* hs = dir ? hsb : hsf;

    // B fragments (weights) resident in VGPRs for the whole T loop
    half8 bf[4];
    float bias[4];
#pragma unroll
    for (int p = 0; p < 4; ++p) {
        bf[p] = *(const half8*)(W1 + (p * 16 + col) * 32 + q * 8);
        bias[p] = b1[p * 16 + col];
    }
    float c[4];
#pragma unroll
    for (int r = 0; r < 4; ++r)
        c[r] = c0[(size_t)(base + w * 16 + q * 4 + r) * 16 + col];

    // zero K-pad columns 24..31 of both buffers (weights there are 0, but avoid inf*0)
    if (tid < 128) {
        unsigned int* p = (unsigned int*)&Xs[tid >> 6][tid & 63][24];
        p[0] = 0u; p[1] = 0u; p[2] = 0u; p[3] = 0u;
    }
    // stage h0 into Xs[0] cols 8..23
    {
        int row = tid & 63, u0 = (tid >> 6) * 4;
        float4 v = *(const float4*)(h0 + (size_t)(base + row) * 16 + u0);
        h16* d = &Xs[0][row][8 + u0];
        d[0] = (h16)v.x; d[1] = (h16)v.y; d[2] = (h16)v.z; d[3] = (h16)v.w;
    }
    const int srow = tid >> 2, skk = (tid & 3) * 2;
    {
        int t0 = dir ? (TT - 1) : 0;
        float2 v = *(const float2*)(x + ((size_t)t0 * BB + base + srow) * 8 + skk);
        Xs[0][srow][skk] = (h16)v.x;
        Xs[0][srow][skk + 1] = (h16)v.y;
    }
    __syncthreads();

    for (int s = 0; s < TT; ++s) {
        const int t = dir ? (TT - 1 - s) : s;
        const int cur = s & 1, nxt = cur ^ 1;
        if (s < TT - 1) {
            int tn = dir ? (t - 1) : (t + 1);
            float2 v = *(const float2*)(x + ((size_t)tn * BB + base + srow) * 8 + skk);
            Xs[nxt][srow][skk] = (h16)v.x;
            Xs[nxt][srow][skk + 1] = (h16)v.y;
        }
        half8 af = *(const half8*)&Xs[cur][w * 16 + col][q * 8];
        f32x4 acc[4];
#pragma unroll
        for (int p = 0; p < 4; ++p) {
            f32x4 z = {0.f, 0.f, 0.f, 0.f};
            acc[p] = __builtin_amdgcn_mfma_f32_16x16x32_f16(af, bf[p], z, 0, 0, 0);
        }
#pragma unroll
        for (int r = 0; r < 4; ++r) {
            float h = lstm_up(acc[0][r] + bias[0], acc[1][r] + bias[1],
                              acc[2][r] + bias[2], acc[3][r] + bias[3], c[r]);
            hst[col][w * 16 + q * 4 + r] = (h16)h;
            if (s < TT - 1) Xs[nxt][w * 16 + q * 4 + r][8 + col] = (h16)h;
        }
        __syncthreads();
        { // coalesced flush of this step's hs tile: [16 units][64 batch] -> [T][16][B]
            int u = tid >> 4, b0 = (tid & 15) * 4;
            unsigned long long vv = *(const unsigned long long*)&hst[u][b0];
            *(unsigned long long*)(hs + ((size_t)t * 16 + u) * BB + base + b0) = vv;
        }
        __syncthreads();
    }
}

// ---------------- middle LSTM + dense, MFMA 16x16x32 f16 ----------------
// block = 256 (4 waves): wave w -> (m-tile = w&1 of 2, unit-half nh = w>>1 of 2).
// Each wave holds its 24 weight B-fragments (96 VGPRs) for the whole T loop.
// X[32][96] = [hs_f(16)|hs_b(16)|h2(64)] fp16 in double-buffered LDS.
__global__ __launch_bounds__(256, 2) void mid_lstm_kernel(
    const h16* __restrict__ hsf, const h16* __restrict__ hsb,
    const float* __restrict__ h0m, const float* __restrict__ c0m,
    const h16* __restrict__ W2, const float* __restrict__ b2,
    const float* __restrict__ Wd, const float* __restrict__ bdp,
    float* __restrict__ out)
{
    __shared__ h16 Xs[2][32][104];       // +8 pad -> 2-way-max LDS bank aliasing on b128 reads
    __shared__ float outbuf[32][55];     // 54-step output tile, flushed coalesced
    __shared__ float outacc[2][32];      // cross-wave dense partial (double-buffered)

    const int tid = threadIdx.x;
    const int base = blockIdx.x * 32;
    const int wv = tid >> 6, lane = tid & 63, col = lane & 15, q = lane >> 4;
    const int mt = wv & 1, nh = wv >> 1;

    half8 bfr[4][2][3];
    float bias[4][2];
    float wd[2];
#pragma unroll
    for (int p = 0; p < 4; ++p)
#pragma unroll
        for (int a = 0; a < 2; ++a) {
            int n = p * 64 + nh * 32 + a * 16 + col;
#pragma unroll
            for (int kt = 0; kt < 3; ++kt)
                bfr[p][a][kt] = *(const half8*)(W2 + (size_t)n * 96 + kt * 32 + q * 8);
            bias[p][a] = b2[n];
        }
#pragma unroll
    for (int a = 0; a < 2; ++a)
        wd[a] = Wd[nh * 32 + a * 16 + col];
    const float bdv = bdp[0];

    float c[2][4];
#pragma unroll
    for (int a = 0; a < 2; ++a)
#pragma unroll
        for (int r = 0; r < 4; ++r)
            c[a][r] = c0m[(size_t)(base + mt * 16 + q * 4 + r) * 64 + nh * 32 + a * 16 + col];

    const int su = tid >> 4, sb0 = (tid & 15) * 2;
    // initial stage: hs(0) and h0m into Xs[0]
    {
        unsigned int vf = *(const unsigned int*)(hsf + ((size_t)0 * 16 + su) * BB + base + sb0);
        unsigned int vb = *(const unsigned int*)(hsb + ((size_t)0 * 16 + su) * BB + base + sb0);
        union { unsigned int u; h16 h[2]; } cf, cb;
        cf.u = vf; cb.u = vb;
        Xs[0][sb0][su] = cf.h[0];      Xs[0][sb0 + 1][su] = cf.h[1];
        Xs[0][sb0][16 + su] = cb.h[0]; Xs[0][sb0 + 1][16 + su] = cb.h[1];
    }
    {
        int row = tid >> 3, u0 = (tid & 7) * 8;
        float4 v0 = *(const float4*)(h0m + (size_t)(base + row) * 64 + u0);
        float4 v1 = *(const float4*)(h0m + (size_t)(base + row) * 64 + u0 + 4);
        h16* d = &Xs[0][row][32 + u0];
        d[0] = (h16)v0.x; d[1] = (h16)v0.y; d[2] = (h16)v0.z; d[3] = (h16)v0.w;
        d[4] = (h16)v1.x; d[5] = (h16)v1.y; d[6] = (h16)v1.z; d[7] = (h16)v1.w;
    }
    __syncthreads();

    for (int t = 0; t < TT; ++t) {
        const int cur = t & 1, nxt = cur ^ 1;
        const int tc = t % 54;
        if (t < TT - 1) {  // prefetch hs(t+1) into the other buffer
            unsigned int vf = *(const unsigned int*)(hsf + ((size_t)(t + 1) * 16 + su) * BB + base + sb0);
            unsigned int vb = *(const unsigned int*)(hsb + ((size_t)(t + 1) * 16 + su) * BB + base + sb0);
            union { unsigned int u; h16 h[2]; } cf, cb;
            cf.u = vf; cb.u = vb;
            Xs[nxt][sb0][su] = cf.h[0];      Xs[nxt][sb0 + 1][su] = cf.h[1];
            Xs[nxt][sb0][16 + su] = cb.h[0]; Xs[nxt][sb0 + 1][16 + su] = cb.h[1];
        }
        half8 af[3];
#pragma unroll
        for (int kt = 0; kt < 3; ++kt)
            af[kt] = *(const half8*)&Xs[cur][mt * 16 + col][kt * 32 + q * 8];
        f32x4 acc[4][2];
#pragma unroll
        for (int p = 0; p < 4; ++p)
#pragma unroll
            for (int a = 0; a < 2; ++a) {
                f32x4 z = {0.f, 0.f, 0.f, 0.f};
                z = __builtin_amdgcn_mfma_f32_16x16x32_f16(af[0], bfr[p][a][0], z, 0, 0, 0);
                z = __builtin_amdgcn_mfma_f32_16x16x32_f16(af[1], bfr[p][a][1], z, 0, 0, 0);
                z = __builtin_amdgcn_mfma_f32_16x16x32_f16(af[2], bfr[p][a][2], z, 0, 0, 0);
                acc[p][a] = z;
            }
        float dp[4] = {0.f, 0.f, 0.f, 0.f};
#pragma unroll
        for (int a = 0; a < 2; ++a)
#pragma unroll
            for (int r = 0; r < 4; ++r) {
                float h = lstm_up(acc[0][a][r] + bias[0][a], acc[1][a][r] + bias[1][a],
                                  acc[2][a][r] + bias[2][a], acc[3][a][r] + bias[3][a], c[a][r]);
                dp[r] = fmaf(h, wd[a], dp[r]);
                if (t < TT - 1)
                    Xs[nxt][mt * 16 + q * 4 + r][32 + nh * 32 + a * 16 + col] = (h16)h;
            }
        // dense: reduce over the 16 unit-columns of this wave's half
#pragma unroll
        for (int mask = 1; mask < 16; mask <<= 1)
#pragma unroll
            for (int r = 0; r < 4; ++r)
                dp[r] += __shfl_xor(dp[r], mask, 16);
        if (nh == 0 && col == 0)
#pragma unroll
            for (int r = 0; r < 4; ++r)
                outacc[t & 1][mt * 16 + q * 4 + r] = dp[r];
        __syncthreads();
        if (nh == 1 && col == 0)
#pragma unroll
            for (int r = 0; r < 4; ++r) {
                int bl = mt * 16 + q * 4 + r;
                outbuf[bl][tc] = dp[r] + outacc[t & 1][bl] + bdv;
            }
        if (tc == 53) {  // coalesced flush of 54 time steps
            __syncthreads();
            for (int idx = tid; idx < 32 * 54; idx += 256) {
                int row = idx / 54, cc = idx - row * 54;
                out[(size_t)(base + row) * TT + (t - 53) + cc] = outbuf[row][cc];
            }
        }
    }
}

extern "C" void kernel_launch(void* const* d_in, const int* in_sizes, int n_in,
                              void* d_out, int out_size, void* d_ws, size_t ws_size,
                              hipStream_t stream)
{
    const float* x     = (const float*)d_in[0];
    const float* h0f   = (const float*)d_in[1];
    const float* c0f   = (const float*)d_in[2];
    const float* h0b   = (const float*)d_in[3];
    const float* c0b   = (const float*)d_in[4];
    const float* h0m   = (const float*)d_in[5];
    const float* c0m   = (const float*)d_in[6];
    const float* Wih_f = (const float*)d_in[7];
    const float* Whh_f = (const float*)d_in[8];
    const float* bih_f = (const float*)d_in[9];
    const float* bhh_f = (const float*)d_in[10];
    const float* Wih_b = (const float*)d_in[11];
    const float* Whh_b = (const float*)d_in[12];
    const float* bih_b = (const float*)d_in[13];
    const float* bhh_b = (const float*)d_in[14];
    const float* Wih_m = (const float*)d_in[15];
    const float* Whh_m = (const float*)d_in[16];
    const float* bih_m = (const float*)d_in[17];
    const float* bhh_m = (const float*)d_in[18];
    const float* Wd    = (const float*)d_in[19];
    const float* bd    = (const float*)d_in[20];

    char* ws = (char*)d_ws;
    h16* W1f   = (h16*)(ws + 0);        // 64*32*2   = 4096
    h16* W1b   = (h16*)(ws + 4096);     // 4096
    h16* W2    = (h16*)(ws + 8192);     // 256*96*2  = 49152
    float* b1f = (float*)(ws + 57344);  // 256
    float* b1b = (float*)(ws + 57600);  // 256
    float* b2  = (float*)(ws + 57856);  // 1024
    h16* hsf   = (h16*)(ws + 58880);                              // T*16*B*2 = 113246208
    h16* hsb   = (h16*)(ws + 58880 + (size_t)TT * 16 * BB * 2);   // same
    // total ws use: ~226.6 MB

    prep_kernel<<<64, 256, 0, stream>>>(Wih_f, Whh_f, bih_f, bhh_f,
                                        Wih_b, Whh_b, bih_b, bhh_b,
                                        Wih_m, Whh_m, bih_m, bhh_m,
                                        W1f, W1b, W2, b1f, b1b, b2);
    small_lstm_kernel<<<512, 256, 0, stream>>>(x, h0f, c0f, h0b, c0b,
                                               W1f, b1f, W1b, b1b, hsf, hsb);
    mid_lstm_kernel<<<512, 256, 0, stream>>>(hsf, hsb, h0m, c0m, W2, b2,
                                             Wd, bd, (float*)d_out);
}

// Round 3
// 907.034 us; speedup vs baseline: 1.1200x; 1.1200x over previous
//
#include <hip/hip_runtime.h>

#define TT 216
#define BB 16384
#define LOG2E 1.44269504088896340736f

typedef _Float16 h16;
typedef _Float16 half8 __attribute__((ext_vector_type(8)));
typedef float f32x4 __attribute__((ext_vector_type(4)));
// Vector types get char-TBAA in clang (alias everything) -> safe for LDS type
// punning WITHOUT barriers. Scalar puns (unsigned long long) carry their own
// TBAA tag, do NOT alias _Float16 stores, and get reordered -> round-2 bug.
typedef unsigned short u16x4a __attribute__((ext_vector_type(4)));

__device__ __forceinline__ float rcp_f(float v) { return __builtin_amdgcn_rcpf(v); }

// Gate preactivations arrive PRE-SCALED: pi,pf,po = -log2e*(preact), pg = 2*log2e*(preact).
// sigmoid(i) = 1/(1+2^pi), tanh(g) = (Eg-2)/Eg with Eg = 1+2^pg.
// c' = c/Ef + (Eg-2)/(Ei*Eg)  -> single rcp via common denominator.
// h  = (Ec-2)/(Eo*Ec),  Ec = 1+2^(2*log2e*c') (clamped to avoid inf*0=NaN).
__device__ __forceinline__ float lstm_up(float pi, float pf, float pg, float po, float& c)
{
    float ei = exp2f(pi), ef = exp2f(pf), eg = exp2f(pg);
    float Ei = 1.f + ei, Ef = 1.f + ef, Eg = 1.f + eg;
    float EiEg = Ei * Eg;
    float N = fmaf(c, EiEg, Ef * (Eg - 2.f));
    c = N * rcp_f(Ef * EiEg);
    float Eo = 1.f + exp2f(po);
    float pc = fminf(c * (2.f * LOG2E), 60.f);
    float Ec = 1.f + exp2f(pc);
    return (Ec - 2.f) * rcp_f(Eo * Ec);
}

// ---------------- weight prep: fp32 -> fp16, [N][K] fragment-ready, exp2-prescaled ----------
__global__ void prep_kernel(
    const float* __restrict__ Wih_f, const float* __restrict__ Whh_f,
    const float* __restrict__ bih_f, const float* __restrict__ bhh_f,
    const float* __restrict__ Wih_b, const float* __restrict__ Whh_b,
    const float* __restrict__ bih_b, const float* __restrict__ bhh_b,
    const float* __restrict__ Wih_m, const float* __restrict__ Whh_m,
    const float* __restrict__ bih_m, const float* __restrict__ bhh_m,
    h16* __restrict__ W1f, h16* __restrict__ W1b, h16* __restrict__ W2,
    float* __restrict__ b1f, float* __restrict__ b1b, float* __restrict__ b2)
{
    int gtid = blockIdx.x * blockDim.x + threadIdx.x;
    int gs = gridDim.x * blockDim.x;
    for (int idx = gtid; idx < 64 * 32; idx += gs) {
        int n = idx >> 5, k = idx & 31;
        float a = ((n >> 4) == 2) ? 2.f * LOG2E : -LOG2E;
        float vf = 0.f, vb = 0.f;
        if (k < 8)       { vf = Wih_f[n * 8 + k];      vb = Wih_b[n * 8 + k]; }
        else if (k < 24) { vf = Whh_f[n * 16 + k - 8]; vb = Whh_b[n * 16 + k - 8]; }
        W1f[idx] = (h16)(vf * a);
        W1b[idx] = (h16)(vb * a);
    }
    for (int n = gtid; n < 64; n += gs) {
        float a = ((n >> 4) == 2) ? 2.f * LOG2E : -LOG2E;
        b1f[n] = (bih_f[n] + bhh_f[n]) * a;
        b1b[n] = (bih_b[n] + bhh_b[n]) * a;
    }
    for (int idx = gtid; idx < 256 * 96; idx += gs) {
        int n = idx / 96, k = idx - n * 96;
        float a = ((n >> 6) == 2) ? 2.f * LOG2E : -LOG2E;
        float v = (k < 32) ? Wih_m[n * 32 + k] : Whh_m[n * 64 + k - 32];
        W2[idx] = (h16)(v * a);
    }
    for (int n = gtid; n < 256; n += gs) {
        float a = ((n >> 6) == 2) ? 2.f * LOG2E : -LOG2E;
        b2[n] = (bih_m[n] + bhh_m[n]) * a;
    }
}

// ---------------- small LSTMs (fwd + bwd), barrier-free, one 16-batch tile per wave -------
// 2048 independent waves (1024 per dir). hs layout: [T][B][16] fp16.
// Same-wave LDS write->read needs no barrier (DS pipe is in-order per wave);
// all cross-type LDS accesses use vector puns (char TBAA) so the compiler
// cannot reorder them either.
__global__ __launch_bounds__(256, 2) void small_lstm_kernel(
    const float* __restrict__ x,
    const float* __restrict__ h0f, const float* __restrict__ c0f,
    const float* __restrict__ h0b, const float* __restrict__ c0b,
    const h16* __restrict__ W1f, const float* __restrict__ b1f,
    const h16* __restrict__ W1b, const float* __restrict__ b1b,
    h16* __restrict__ hsf, h16* __restrict__ hsb)
{
    __shared__ __attribute__((aligned(16))) h16 Xs[4][2][16][40];  // per-wave private dbuf A-tile

    const int tid = threadIdx.x;
    const int wv = tid >> 6, lane = tid & 63, col = lane & 15, q = lane >> 4;
    const int wid = blockIdx.x * 4 + wv;
    const int dir = wid >> 10;
    const int base = (wid & 1023) * 16;

    const float* h0 = dir ? h0b : h0f;
    const float* c0 = dir ? c0b : c0f;
    const h16* W1   = dir ? W1b : W1f;
    const float* b1 = dir ? b1b : b1f;
    h16* hs = dir ? hsb : hsf;

    half8 bf[4]; float bias[4];
#pragma unroll
    for (int p = 0; p < 4; ++p) {
        bf[p] = *(const half8*)(W1 + (p * 16 + col) * 32 + q * 8);
        bias[p] = b1[p * 16 + col];
    }
    float c[4];
#pragma unroll
    for (int r = 0; r < 4; ++r)
        c[r] = c0[(size_t)(base + q * 4 + r) * 16 + col];

    // zero K-pad cols 24..31 of both buffers (vector pun -> char TBAA, ordered)
    {
        int buf = lane >> 5, row = lane & 15, c4 = ((lane >> 4) & 1) * 4;
        *(u16x4a*)&Xs[wv][buf][row][24 + c4] = (u16x4a)0;
    }
    // h0 into Xs[0] cols 8..23
    {
        int row = lane >> 2, u0 = (lane & 3) * 4;
        float4 v = *(const float4*)(h0 + (size_t)(base + row) * 16 + u0);
        h16* d = &Xs[wv][0][row][8 + u0];
        d[0] = (h16)v.x; d[1] = (h16)v.y; d[2] = (h16)v.z; d[3] = (h16)v.w;
    }
    const int srow = lane >> 2, skk = (lane & 3) * 2;
    {   // x(step 0) into Xs[0]
        int t0 = dir ? (TT - 1) : 0;
        float2 v = *(const float2*)(x + ((size_t)t0 * BB + base + srow) * 8 + skk);
        Xs[wv][0][srow][skk]     = (h16)v.x;
        Xs[wv][0][srow][skk + 1] = (h16)v.y;
    }
    // x register pipeline: xr1 = x(step 1), xr2 = x(step 2)
    float2 xr1, xr2;
    {
        int t1 = dir ? (TT - 2) : 1;
        int t2 = dir ? (TT - 3) : 2;
        xr1 = *(const float2*)(x + ((size_t)t1 * BB + base + srow) * 8 + skk);
        xr2 = *(const float2*)(x + ((size_t)t2 * BB + base + srow) * 8 + skk);
    }

    for (int s = 0; s < TT; ++s) {
        const int t = dir ? (TT - 1 - s) : s;
        const int cur = s & 1, nxt = cur ^ 1;
        if (s < TT - 1) {   // x for step s+1
            Xs[wv][nxt][srow][skk]     = (h16)xr1.x;
            Xs[wv][nxt][srow][skk + 1] = (h16)xr1.y;
        }
        xr1 = xr2;
        {   // issue x(step s+3), clamped
            int sl = (s + 3 < TT) ? (s + 3) : (TT - 1);
            int tl = dir ? (TT - 1 - sl) : sl;
            xr2 = *(const float2*)(x + ((size_t)tl * BB + base + srow) * 8 + skk);
        }
        half8 af = *(const half8*)&Xs[wv][cur][col][q * 8];
        f32x4 acc[4];
#pragma unroll
        for (int p = 0; p < 4; ++p) {
            f32x4 z = {0.f, 0.f, 0.f, 0.f};
            acc[p] = __builtin_amdgcn_mfma_f32_16x16x32_f16(af, bf[p], z, 0, 0, 0);
        }
#pragma unroll
        for (int r = 0; r < 4; ++r) {
            float h = lstm_up(acc[0][r] + bias[0], acc[1][r] + bias[1],
                              acc[2][r] + bias[2], acc[3][r] + bias[3], c[r]);
            Xs[wv][nxt][q * 4 + r][8 + col] = (h16)h;   // A-layout for next step
        }
        {   // coalesced hs(t) store via LDS transpose; vector pun = char TBAA,
            // so this read cannot be hoisted above the h-writes (round-2 bug).
            int b = lane >> 2, u4 = (lane & 3) * 4;
            u16x4a vv = *(const u16x4a*)&Xs[wv][nxt][b][8 + u4];
            *(u16x4a*)(hs + ((size_t)t * BB + base + b) * 16 + u4) = vv;
        }
    }
}

// ---------------- middle LSTM + dense, 16-batch blocks, dense via MFMA ----------------
// block = 256 (4 waves): wave w handles units [16w,16w+16) for all 4 gates (12 MFMA/step).
// X[16][96] = [hs_f(16)|hs_b(16)|h2(64)] fp16, double-buffered. One barrier per step.
// Dense out(t-1) = wd . h2(t-1) = 2 extra MFMA on wave 3 over X(t) k=32..95.
// All cross-type LDS producer->consumer edges here cross a __syncthreads(),
// which is a full compiler memory fence -> puns are safe.
__global__ __launch_bounds__(256, 4) void mid_lstm_kernel(
    const h16* __restrict__ hsf, const h16* __restrict__ hsb,
    const float* __restrict__ h0m, const float* __restrict__ c0m,
    const h16* __restrict__ W2, const float* __restrict__ b2,
    const float* __restrict__ Wd, const float* __restrict__ bdp,
    float* __restrict__ out)
{
    __shared__ __attribute__((aligned(16))) h16 Xs[2][16][104];
    __shared__ float outbuf[16][55];

    const int tid = threadIdx.x;
    const int base = blockIdx.x * 16;
    const int wv = tid >> 6, lane = tid & 63, col = lane & 15, q = lane >> 4;

    half8 bfr[4][3]; float bias[4];
#pragma unroll
    for (int p = 0; p < 4; ++p) {
        int n = p * 64 + wv * 16 + col;
#pragma unroll
        for (int kt = 0; kt < 3; ++kt)
            bfr[p][kt] = *(const half8*)(W2 + (size_t)n * 96 + kt * 32 + q * 8);
        bias[p] = b2[n];
    }
    half8 dfr[2];   // dense B-fragment: column 0 = wd over k in [32,96)
#pragma unroll
    for (int kt = 0; kt < 2; ++kt)
#pragma unroll
        for (int j = 0; j < 8; ++j)
            dfr[kt][j] = (col == 0) ? (h16)Wd[kt * 32 + q * 8 + j] : (h16)0.f;
    const float bdv = bdp[0];

    float c[4];
#pragma unroll
    for (int r = 0; r < 4; ++r)
        c[r] = c0m[(size_t)(base + q * 4 + r) * 64 + wv * 16 + col];

    const h16* hsrc = (wv == 1) ? hsb : hsf;
    const int srow = lane >> 1, su8 = (lane & 1) * 8;
    // initial staging: hs(0) + h0m into Xs[0]
    if (wv < 2 && lane < 32) {
        uint4 v = *(const uint4*)(hsrc + ((size_t)0 * BB + base + srow) * 16 + su8);
        *(uint4*)&Xs[0][srow][wv * 16 + su8] = v;
    }
    {
        int row = tid >> 4, u4 = (tid & 15) * 4;
        float4 v = *(const float4*)(h0m + (size_t)(base + row) * 64 + u4);
        h16* d = &Xs[0][row][32 + u4];
        d[0] = (h16)v.x; d[1] = (h16)v.y; d[2] = (h16)v.z; d[3] = (h16)v.w;
    }
    // hs register pipeline (2 steps deep) on waves 0,1
    uint4 ra, rb;
    if (wv < 2 && lane < 32) {
        ra = *(const uint4*)(hsrc + ((size_t)1 * BB + base + srow) * 16 + su8);
        rb = *(const uint4*)(hsrc + ((size_t)2 * BB + base + srow) * 16 + su8);
    }
    __syncthreads();

    for (int t = 0; t < TT; ++t) {
        const int cur = t & 1, nxt = cur ^ 1;
        if (wv < 2 && lane < 32) {
            if (t < TT - 1)
                *(uint4*)&Xs[nxt][srow][wv * 16 + su8] = ra;   // hs(t+1)
            ra = rb;
            int tl = (t + 3 < TT) ? (t + 3) : (TT - 1);
            rb = *(const uint4*)(hsrc + ((size_t)tl * BB + base + srow) * 16 + su8);
        }
        half8 af[3];
#pragma unroll
        for (int kt = 0; kt < 3; ++kt)
            af[kt] = *(const half8*)&Xs[cur][col][kt * 32 + q * 8];
        // dense for out(t-1): X(t) k=32..95 holds h2(t-1)
        if (wv == 3 && t > 0) {
            f32x4 z = {0.f, 0.f, 0.f, 0.f};
            z = __builtin_amdgcn_mfma_f32_16x16x32_f16(af[1], dfr[0], z, 0, 0, 0);
            z = __builtin_amdgcn_mfma_f32_16x16x32_f16(af[2], dfr[1], z, 0, 0, 0);
            if (col == 0) {
                int tc = (t - 1) % 54;
#pragma unroll
                for (int r = 0; r < 4; ++r)
                    outbuf[q * 4 + r][tc] = z[r] + bdv;
            }
        }
        f32x4 acc[4];
#pragma unroll
        for (int p = 0; p < 4; ++p) {
            f32x4 z = {0.f, 0.f, 0.f, 0.f};
            z = __builtin_amdgcn_mfma_f32_16x16x32_f16(af[0], bfr[p][0], z, 0, 0, 0);
            z = __builtin_amdgcn_mfma_f32_16x16x32_f16(af[1], bfr[p][1], z, 0, 0, 0);
            z = __builtin_amdgcn_mfma_f32_16x16x32_f16(af[2], bfr[p][2], z, 0, 0, 0);
            acc[p] = z;
        }
#pragma unroll
        for (int r = 0; r < 4; ++r) {
            float h = lstm_up(acc[0][r] + bias[0], acc[1][r] + bias[1],
                              acc[2][r] + bias[2], acc[3][r] + bias[3], c[r]);
            Xs[nxt][q * 4 + r][32 + wv * 16 + col] = (h16)h;
        }
        if (t > 0 && (t % 54) == 0) {   // flush out(t-54 .. t-1)
            __syncthreads();
            int off = t - 54;
            for (int idx = tid; idx < 16 * 54; idx += 256) {
                int row = idx / 54, cc = idx - row * 54;
                out[(size_t)(base + row) * TT + off + cc] = outbuf[row][cc];
            }
        }
        __syncthreads();
    }
    // epilogue: out(215) from Xs[0] (h2(215) staged there at t=215)
    if (wv == 3) {
        half8 a1 = *(const half8*)&Xs[0][col][32 + q * 8];
        half8 a2 = *(const half8*)&Xs[0][col][64 + q * 8];
        f32x4 z = {0.f, 0.f, 0.f, 0.f};
        z = __builtin_amdgcn_mfma_f32_16x16x32_f16(a1, dfr[0], z, 0, 0, 0);
        z = __builtin_amdgcn_mfma_f32_16x16x32_f16(a2, dfr[1], z, 0, 0, 0);
        if (col == 0)
#pragma unroll
            for (int r = 0; r < 4; ++r)
                outbuf[q * 4 + r][53] = z[r] + bdv;
    }
    __syncthreads();
    for (int idx = tid; idx < 16 * 54; idx += 256) {
        int row = idx / 54, cc = idx - row * 54;
        out[(size_t)(base + row) * TT + 162 + cc] = outbuf[row][cc];
    }
}

extern "C" void kernel_launch(void* const* d_in, const int* in_sizes, int n_in,
                              void* d_out, int out_size, void* d_ws, size_t ws_size,
                              hipStream_t stream)
{
    const float* x     = (const float*)d_in[0];
    const float* h0f   = (const float*)d_in[1];
    const float* c0f   = (const float*)d_in[2];
    const float* h0b   = (const float*)d_in[3];
    const float* c0b   = (const float*)d_in[4];
    const float* h0m   = (const float*)d_in[5];
    const float* c0m   = (const float*)d_in[6];
    const float* Wih_f = (const float*)d_in[7];
    const float* Whh_f = (const float*)d_in[8];
    const float* bih_f = (const float*)d_in[9];
    const float* bhh_f = (const float*)d_in[10];
    const float* Wih_b = (const float*)d_in[11];
    const float* Whh_b = (const float*)d_in[12];
    const float* bih_b = (const float*)d_in[13];
    const float* bhh_b = (const float*)d_in[14];
    const float* Wih_m = (const float*)d_in[15];
    const float* Whh_m = (const float*)d_in[16];
    const float* bih_m = (const float*)d_in[17];
    const float* bhh_m = (const float*)d_in[18];
    const float* Wd    = (const float*)d_in[19];
    const float* bd    = (const float*)d_in[20];

    char* ws = (char*)d_ws;
    h16* W1f   = (h16*)(ws + 0);
    h16* W1b   = (h16*)(ws + 4096);
    h16* W2    = (h16*)(ws + 8192);
    float* b1f = (float*)(ws + 57344);
    float* b1b = (float*)(ws + 57600);
    float* b2  = (float*)(ws + 57856);
    h16* hsf   = (h16*)(ws + 58880);                              // [T][B][16] fp16
    h16* hsb   = (h16*)(ws + 58880 + (size_t)TT * BB * 16 * 2);   // [T][B][16] fp16

    prep_kernel<<<64, 256, 0, stream>>>(Wih_f, Whh_f, bih_f, bhh_f,
                                        Wih_b, Whh_b, bih_b, bhh_b,
                                        Wih_m, Whh_m, bih_m, bhh_m,
                                        W1f, W1b, W2, b1f, b1b, b2);
    small_lstm_kernel<<<512, 256, 0, stream>>>(x, h0f, c0f, h0b, c0b,
                                               W1f, b1f, W1b, b1b, hsf, hsb);
    mid_lstm_kernel<<<1024, 256, 0, stream>>>(hsf, hsb, h0m, c0m, W2, b2,
                                              Wd, bd, (float*)d_out);
}

// Round 4
// 688.640 us; speedup vs baseline: 1.4752x; 1.3171x over previous
//
#include <hip/hip_runtime.h>

#define TT 216
#define BB 16384
#define LOG2E 1.44269504088896340736f

typedef _Float16 h16;
typedef _Float16 half8 __attribute__((ext_vector_type(8)));
typedef float f32x4 __attribute__((ext_vector_type(4)));
// Vector types get char-TBAA in clang (alias everything) -> safe for LDS type
// punning. Scalar puns (unsigned long long) carry their own TBAA tag and get
// reordered across _Float16 stores (round-2 bug) -- never use scalar puns.

__device__ __forceinline__ float rcp_f(float v) { return __builtin_amdgcn_rcpf(v); }
__device__ __forceinline__ float ex2(float v)   { return __builtin_amdgcn_exp2f(v); }

// Gate preactivations arrive PRE-SCALED: pi,pf,po = -log2e*(preact), pg = 2*log2e*(preact).
// State cs = 2*log2e * c (pre-scaled cell state).
// sigmoid(i) = 1/(1+2^pi); tanh(g) = (Eg-2)/Eg, Eg = 1+2^pg.
// cs' = cs/Ef + 2L*(Eg-2)/(Ei*Eg) -> single rcp via common denominator.
// h = (Ec-2)/(Eo*Ec), Ec = 1+2^min(cs',60)  (clamp: keeps Eo*Ec finite).
__device__ __forceinline__ float lstm_up(float pi, float pf, float pg, float po, float& cs)
{
    float ei = ex2(pi), ef = ex2(pf), eg = ex2(pg), eo = ex2(po);
    float Ei = 1.f + ei, Ef = 1.f + ef, Eg = 1.f + eg, Eo = 1.f + eo;
    float EiEg = Ei * Eg;
    float G = fmaf(2.f * LOG2E, Eg, -4.f * LOG2E);   // 2L*(Eg-2)
    float N = fmaf(cs, EiEg, Ef * G);
    cs = N * rcp_f(Ef * EiEg);
    float pc = fminf(cs, 60.f);
    float Ec = 1.f + ex2(pc);
    return (Ec - 2.f) * rcp_f(Eo * Ec);
}

// ---------------- weight prep: fp32 -> fp16, fragment-ready, exp2-prescaled, bias-in-K ----
__global__ void prep_kernel(
    const float* __restrict__ Wih_f, const float* __restrict__ Whh_f,
    const float* __restrict__ bih_f, const float* __restrict__ bhh_f,
    const float* __restrict__ Wih_b, const float* __restrict__ Whh_b,
    const float* __restrict__ bih_b, const float* __restrict__ bhh_b,
    const float* __restrict__ Wih_m, const float* __restrict__ Whh_m,
    const float* __restrict__ bih_m, const float* __restrict__ bhh_m,
    h16* __restrict__ W1f, h16* __restrict__ W1b, h16* __restrict__ W2)
{
    int gtid = blockIdx.x * blockDim.x + threadIdx.x;
    int gs = gridDim.x * blockDim.x;
    // small LSTMs: W1[n=64][k=32]: k<8 x, 8..23 h, 24 bias (X col24==1), 25..31 zero
    for (int idx = gtid; idx < 64 * 32; idx += gs) {
        int n = idx >> 5, k = idx & 31;
        float a = ((n >> 4) == 2) ? 2.f * LOG2E : -LOG2E;
        float vf = 0.f, vb = 0.f;
        if (k < 8)        { vf = Wih_f[n * 8 + k];       vb = Wih_b[n * 8 + k]; }
        else if (k < 24)  { vf = Whh_f[n * 16 + k - 8];  vb = Whh_b[n * 16 + k - 8]; }
        else if (k == 24) { vf = bih_f[n] + bhh_f[n];    vb = bih_b[n] + bhh_b[n]; }
        W1f[idx] = (h16)(vf * a);
        W1b[idx] = (h16)(vb * a);
    }
    // middle LSTM: W2[n=256][k=128]: k<32 [hs_f|hs_b], 32..95 h2, 96 bias, 97..127 zero
    for (int idx = gtid; idx < 256 * 128; idx += gs) {
        int n = idx >> 7, k = idx & 127;
        float a = ((n >> 6) == 2) ? 2.f * LOG2E : -LOG2E;
        float v = 0.f;
        if (k < 32)       v = Wih_m[n * 32 + k];
        else if (k < 96)  v = Whh_m[n * 64 + k - 32];
        else if (k == 96) v = bih_m[n] + bhh_m[n];
        W2[idx] = (h16)(v * a);
    }
}

// ---------------- small LSTMs (fwd + bwd), 4-wave gate-split, 32 waves/CU ----------------
// grid = 2048 blocks (2 dirs x 1024 batch-tiles of 16). Block = 4 waves; wave g computes
// gate-plane g (1 MFMA), C exchanged via padded LDS; each lane does 1 lstm_up.
// hs layout: [T][B][16] fp16; stored one step lagged from the stable X buffer.
__global__ __launch_bounds__(256, 8) void small_lstm_kernel(
    const float* __restrict__ x,
    const float* __restrict__ h0f, const float* __restrict__ c0f,
    const float* __restrict__ h0b, const float* __restrict__ c0b,
    const h16* __restrict__ W1f, const h16* __restrict__ W1b,
    h16* __restrict__ hsf, h16* __restrict__ hsb)
{
    __shared__ __attribute__((aligned(16))) h16 Xs[2][16][40];   // k: 0..7 x, 8..23 h, 24 one, 25..31 zero
    __shared__ __attribute__((aligned(16))) float Cx[4][16][20]; // [gate][unit][batch] (+pad)

    const int tid = threadIdx.x;
    const int wv = tid >> 6, lane = tid & 63, col = lane & 15, q = lane >> 4;
    const int dir = blockIdx.x & 1;
    const int base = (blockIdx.x >> 1) * 16;

    const float* h0 = dir ? h0b : h0f;
    const float* c0 = dir ? c0b : c0f;
    const h16* W1   = dir ? W1b : W1f;
    h16* hs = dir ? hsb : hsf;

    // wave's gate-plane B fragment (bias folded in at k=24)
    half8 bf = *(const half8*)(W1 + (wv * 16 + col) * 32 + q * 8);

    const int eu = wv * 4 + q, eb = col;   // this lane's (unit, batch) element in phase 2
    float cs = c0[(size_t)(base + eb) * 16 + eu] * (2.f * LOG2E);

    // init pad cols 24..31 (24 = bias-one) in both buffers
    {
        int buf = tid >> 7, row = (tid >> 3) & 15, cc = 24 + (tid & 7);
        Xs[buf][row][cc] = (cc == 24) ? (h16)1.f : (h16)0.f;
    }
    // h0 -> Xs[0] h-region
    {
        int b = tid >> 4, u = tid & 15;
        Xs[0][b][8 + u] = (h16)h0[(size_t)(base + b) * 16 + u];
    }
    // x staging (threads < 128), 2-deep register pipeline
    const int xrow = (tid >> 3) & 15, xk = tid & 7;
    float xr1 = 0.f, xr2 = 0.f;
    if (tid < 128) {
        int t0 = dir ? (TT - 1) : 0;
        int t1 = dir ? (TT - 2) : 1;
        int t2 = dir ? (TT - 3) : 2;
        Xs[0][xrow][xk] = (h16)x[((size_t)t0 * BB + base + xrow) * 8 + xk];
        xr1 = x[((size_t)t1 * BB + base + xrow) * 8 + xk];
        xr2 = x[((size_t)t2 * BB + base + xrow) * 8 + xk];
    }
    __syncthreads();

    const int sb = tid >> 4, su = tid & 15;   // hs-store mapping (contiguous across tid)
    for (int s = 0; s < TT; ++s) {
        const int cur = s & 1, nxt = cur ^ 1;
        // phase 1: Xs[cur] is stable (all writes target Xs[nxt]) -> store hs(s-1)
        if (s > 0) {
            int tp = dir ? (TT - s) : (s - 1);
            hs[((size_t)tp * BB + base + sb) * 16 + su] = Xs[cur][sb][8 + su];
        }
        half8 af = *(const half8*)&Xs[cur][col][q * 8];
        f32x4 z = {0.f, 0.f, 0.f, 0.f};
        z = __builtin_amdgcn_mfma_f32_16x16x32_f16(af, bf, z, 0, 0, 0);
        *(f32x4*)&Cx[wv][col][q * 4] = z;     // C-layout: rows=batch(q*4+r), col=unit
        if (tid < 128 && s < TT - 1) {        // x for step s+1 into Xs[nxt]
            Xs[nxt][xrow][xk] = (h16)xr1;
            xr1 = xr2;
            int sl = (s + 3 < TT) ? (s + 3) : (TT - 1);
            int tl = dir ? (TT - 1 - sl) : sl;
            xr2 = x[((size_t)tl * BB + base + xrow) * 8 + xk];
        }
        __syncthreads();   // Cx ready
        float h = lstm_up(Cx[0][eu][eb], Cx[1][eu][eb], Cx[2][eu][eb], Cx[3][eu][eb], cs);
        Xs[nxt][eb][8 + eu] = (h16)h;
        __syncthreads();   // Xs[nxt] ready for next step
    }
    {   // hs(TT-1): final h sits in Xs[TT&1] = Xs[0]
        int tp = dir ? 0 : (TT - 1);
        hs[((size_t)tp * BB + base + sb) * 16 + su] = Xs[0][sb][8 + su];
    }
}

// ---------------- middle LSTM + dense, 16-batch blocks, K=128 (bias in k=96) -------------
// block = 256 (4 waves): wave w handles units [16w,16w+16) for all 4 gates (16 MFMA/step).
// X[16][128] = [hs_f|hs_b|h2|bias-one|zeros] fp16, double-buffered. One barrier per step.
// Dense out(t-1) = wd . h2(t-1) = 2 extra MFMA on wave 3 over X(t) k=32..95.
__global__ __launch_bounds__(256, 4) void mid_lstm_kernel(
    const h16* __restrict__ hsf, const h16* __restrict__ hsb,
    const float* __restrict__ h0m, const float* __restrict__ c0m,
    const h16* __restrict__ W2,
    const float* __restrict__ Wd, const float* __restrict__ bdp,
    float* __restrict__ out)
{
    __shared__ __attribute__((aligned(16))) h16 Xs[2][16][136];
    __shared__ float outbuf[16][55];

    const int tid = threadIdx.x;
    const int base = blockIdx.x * 16;
    const int wv = tid >> 6, lane = tid & 63, col = lane & 15, q = lane >> 4;

    half8 bfr[4][4];
#pragma unroll
    for (int p = 0; p < 4; ++p) {
        int n = p * 64 + wv * 16 + col;
#pragma unroll
        for (int kt = 0; kt < 4; ++kt)
            bfr[p][kt] = *(const half8*)(W2 + (size_t)n * 128 + kt * 32 + q * 8);
    }
    half8 dfr[2];   // dense B-fragment: column 0 = wd over k in [32,96)
#pragma unroll
    for (int kt = 0; kt < 2; ++kt)
#pragma unroll
        for (int j = 0; j < 8; ++j)
            dfr[kt][j] = (col == 0) ? (h16)Wd[kt * 32 + q * 8 + j] : (h16)0.f;
    const float bdv = bdp[0];

    float cs[4];
#pragma unroll
    for (int r = 0; r < 4; ++r)
        cs[r] = c0m[(size_t)(base + q * 4 + r) * 64 + wv * 16 + col] * (2.f * LOG2E);

    // init cols 96..127 (96 = bias-one) in both buffers
    {
        int buf = tid >> 7, row = (tid >> 3) & 15, cc = 96 + (tid & 7) * 4;
        h16* d = &Xs[buf][row][cc];
        d[0] = ((tid & 7) == 0) ? (h16)1.f : (h16)0.f;
        d[1] = (h16)0.f; d[2] = (h16)0.f; d[3] = (h16)0.f;
    }
    const h16* hsrc = (wv == 1) ? hsb : hsf;
    const int srow = lane >> 1, su8 = (lane & 1) * 8;
    // initial staging: hs(0) + h0m into Xs[0]
    if (wv < 2 && lane < 32) {
        uint4 v = *(const uint4*)(hsrc + ((size_t)0 * BB + base + srow) * 16 + su8);
        *(uint4*)&Xs[0][srow][wv * 16 + su8] = v;
    }
    {
        int row = tid >> 4, u4 = (tid & 15) * 4;
        float4 v = *(const float4*)(h0m + (size_t)(base + row) * 64 + u4);
        h16* d = &Xs[0][row][32 + u4];
        d[0] = (h16)v.x; d[1] = (h16)v.y; d[2] = (h16)v.z; d[3] = (h16)v.w;
    }
    // hs register pipeline (2 steps deep) on waves 0,1
    uint4 ra, rb;
    if (wv < 2 && lane < 32) {
        ra = *(const uint4*)(hsrc + ((size_t)1 * BB + base + srow) * 16 + su8);
        rb = *(const uint4*)(hsrc + ((size_t)2 * BB + base + srow) * 16 + su8);
    }
    __syncthreads();

    for (int t = 0; t < TT; ++t) {
        const int cur = t & 1, nxt = cur ^ 1;
        if (wv < 2 && lane < 32) {
            if (t < TT - 1)
                *(uint4*)&Xs[nxt][srow][wv * 16 + su8] = ra;   // hs(t+1)
            ra = rb;
            int tl = (t + 3 < TT) ? (t + 3) : (TT - 1);
            rb = *(const uint4*)(hsrc + ((size_t)tl * BB + base + srow) * 16 + su8);
        }
        half8 af[4];
#pragma unroll
        for (int kt = 0; kt < 4; ++kt)
            af[kt] = *(const half8*)&Xs[cur][col][kt * 32 + q * 8];
        // dense for out(t-1): X(t) k=32..95 holds h2(t-1)
        if (wv == 3 && t > 0) {
            f32x4 z = {0.f, 0.f, 0.f, 0.f};
            z = __builtin_amdgcn_mfma_f32_16x16x32_f16(af[1], dfr[0], z, 0, 0, 0);
            z = __builtin_amdgcn_mfma_f32_16x16x32_f16(af[2], dfr[1], z, 0, 0, 0);
            if (col == 0) {
                int tc = (t - 1) % 54;
#pragma unroll
                for (int r = 0; r < 4; ++r)
                    outbuf[q * 4 + r][tc] = z[r] + bdv;
            }
        }
        f32x4 acc[4];
#pragma unroll
        for (int p = 0; p < 4; ++p) {
            f32x4 z = {0.f, 0.f, 0.f, 0.f};
            z = __builtin_amdgcn_mfma_f32_16x16x32_f16(af[0], bfr[p][0], z, 0, 0, 0);
            z = __builtin_amdgcn_mfma_f32_16x16x32_f16(af[1], bfr[p][1], z, 0, 0, 0);
            z = __builtin_amdgcn_mfma_f32_16x16x32_f16(af[2], bfr[p][2], z, 0, 0, 0);
            z = __builtin_amdgcn_mfma_f32_16x16x32_f16(af[3], bfr[p][3], z, 0, 0, 0);
            acc[p] = z;
        }
#pragma unroll
        for (int r = 0; r < 4; ++r) {
            float h = lstm_up(acc[0][r], acc[1][r], acc[2][r], acc[3][r], cs[r]);
            Xs[nxt][q * 4 + r][32 + wv * 16 + col] = (h16)h;
        }
        if (t > 0 && (t % 54) == 0) {   // flush out(t-54 .. t-1)
            __syncthreads();
            int off = t - 54;
            for (int idx = tid; idx < 16 * 54; idx += 256) {
                int row = idx / 54, cc = idx - row * 54;
                out[(size_t)(base + row) * TT + off + cc] = outbuf[row][cc];
            }
        }
        __syncthreads();
    }
    // epilogue: out(215) from Xs[0] (h2(215) staged there at t=215)
    if (wv == 3) {
        half8 a1 = *(const half8*)&Xs[0][col][32 + q * 8];
        half8 a2 = *(const half8*)&Xs[0][col][64 + q * 8];
        f32x4 z = {0.f, 0.f, 0.f, 0.f};
        z = __builtin_amdgcn_mfma_f32_16x16x32_f16(a1, dfr[0], z, 0, 0, 0);
        z = __builtin_amdgcn_mfma_f32_16x16x32_f16(a2, dfr[1], z, 0, 0, 0);
        if (col == 0)
#pragma unroll
            for (int r = 0; r < 4; ++r)
                outbuf[q * 4 + r][53] = z[r] + bdv;
    }
    __syncthreads();
    for (int idx = tid; idx < 16 * 54; idx += 256) {
        int row = idx / 54, cc = idx - row * 54;
        out[(size_t)(base + row) * TT + 162 + cc] = outbuf[row][cc];
    }
}

extern "C" void kernel_launch(void* const* d_in, const int* in_sizes, int n_in,
                              void* d_out, int out_size, void* d_ws, size_t ws_size,
                              hipStream_t stream)
{
    const float* x     = (const float*)d_in[0];
    const float* h0f   = (const float*)d_in[1];
    const float* c0f   = (const float*)d_in[2];
    const float* h0b   = (const float*)d_in[3];
    const float* c0b   = (const float*)d_in[4];
    const float* h0m   = (const float*)d_in[5];
    const float* c0m   = (const float*)d_in[6];
    const float* Wih_f = (const float*)d_in[7];
    const float* Whh_f = (const float*)d_in[8];
    const float* bih_f = (const float*)d_in[9];
    const float* bhh_f = (const float*)d_in[10];
    const float* Wih_b = (const float*)d_in[11];
    const float* Whh_b = (const float*)d_in[12];
    const float* bih_b = (const float*)d_in[13];
    const float* bhh_b = (const float*)d_in[14];
    const float* Wih_m = (const float*)d_in[15];
    const float* Whh_m = (const float*)d_in[16];
    const float* bih_m = (const float*)d_in[17];
    const float* bhh_m = (const float*)d_in[18];
    const float* Wd    = (const float*)d_in[19];
    const float* bd    = (const float*)d_in[20];

    char* ws = (char*)d_ws;
    h16* W1f = (h16*)(ws + 0);        // 64*32*2    = 4096
    h16* W1b = (h16*)(ws + 4096);     // 4096
    h16* W2  = (h16*)(ws + 8192);     // 256*128*2  = 65536
    h16* hsf = (h16*)(ws + 73728);                               // [T][B][16] fp16
    h16* hsb = (h16*)(ws + 73728 + (size_t)TT * BB * 16 * 2);    // [T][B][16] fp16

    prep_kernel<<<64, 256, 0, stream>>>(Wih_f, Whh_f, bih_f, bhh_f,
                                        Wih_b, Whh_b, bih_b, bhh_b,
                                        Wih_m, Whh_m, bih_m, bhh_m,
                                        W1f, W1b, W2);
    small_lstm_kernel<<<2048, 256, 0, stream>>>(x, h0f, c0f, h0b, c0b,
                                                W1f, W1b, hsf, hsb);
    mid_lstm_kernel<<<1024, 256, 0, stream>>>(hsf, hsb, h0m, c0m, W2,
                                              Wd, bd, (float*)d_out);
}